// Round 9
// baseline (319.604 us; speedup 1.0000x reference)
//
#include <hip/hip_runtime.h>
#include <math.h>

// Problem constants
#define BB 8
#define KK 4
#define LL 1024
#define DD 512
#define HD 64
#define D3 1536
#define MM (BB*LL*KK)   // 32768 rows for per-state GEMMs
#define BL (BB*LL)      // 8192 (b,l) positions
#define SCALE 0.125f
#define EPSF 1e-8f
#define LN_EPSF 1e-5f

typedef _Float16 hfrag __attribute__((ext_vector_type(8)));
typedef float f32x4 __attribute__((ext_vector_type(4)));

__device__ __forceinline__ unsigned short f2h(float f) {
    _Float16 h = (_Float16)f;
    unsigned short u; __builtin_memcpy(&u, &h, 2); return u;
}
__device__ __forceinline__ float h2f(unsigned short u) {
    _Float16 h; __builtin_memcpy(&h, &u, 2); return (float)h;
}

__device__ __forceinline__ void glds16(const unsigned short* g, unsigned short* l) {
    __builtin_amdgcn_global_load_lds(
        (const __attribute__((address_space(1))) void*)g,
        (__attribute__((address_space(3))) void*)l, 16, 0, 0);
}

// Inline nsw: normalized state weight for (b,k) from sw/pres (32 elems, L2-hot)
__device__ __forceinline__ void nsw_compute(const float* sw, const int* pres,
                                            int b, float* nswv) {
    float w[KK], pr[KK]; float denom = 0.f, ps = 0.f;
    #pragma unroll
    for (int k = 0; k < KK; ++k) {
        pr[k] = pres[b*KK + k] ? 1.f : 0.f;
        w[k]  = sw[b*KK + k] * pr[k];
        denom += w[k]; ps += pr[k];
    }
    #pragma unroll
    for (int k = 0; k < KK; ++k)
        nswv[k] = (denom > EPSF) ? w[k] / fmaxf(denom, EPSF)
                                 : pr[k] / fmaxf(ps, 1.f);
}

// ---------------------------------------------------------------------------
// Fused fp32 -> fp16 weight conversion (row-major).
#define WSZ 262144          // 512*512
#define OG1 1048576         // start of Wg1 (512*1536)
#define OG2 1835008         // start of Wg2
#define WTOT 2097152
__global__ __launch_bounds__(256) void cvt_weights(
        const float* __restrict__ Wq, const float* __restrict__ Wk,
        const float* __restrict__ Wv, const float* __restrict__ Wo,
        const float* __restrict__ Wg1, const float* __restrict__ Wg2,
        unsigned short* __restrict__ dst) {
    int t = blockIdx.x * 256 + threadIdx.x;   // one float4 per thread
    int e = t * 4;
    const float* src; int off;
    if      (e < WSZ)    { src = Wq;  off = e; }
    else if (e < 2*WSZ)  { src = Wk;  off = e - WSZ; }
    else if (e < 3*WSZ)  { src = Wv;  off = e - 2*WSZ; }
    else if (e < OG1)    { src = Wo;  off = e - 3*WSZ; }
    else if (e < OG2)    { src = Wg1; off = e - OG1; }
    else                 { src = Wg2; off = e - OG2; }
    float4 v = *(const float4*)(src + off);
    ushort4 o;
    o.x = f2h(v.x); o.y = f2h(v.y); o.z = f2h(v.z); o.w = f2h(v.w);
    *(ushort4*)(dst + e) = o;
}

// ---------------------------------------------------------------------------
// Build x (fp16) + weighted_mean/max_feat (fp32, exact) + rowmask + f_nsw.
__global__ __launch_bounds__(256) void buildx_kernel(
        const float* __restrict__ SR, const int* __restrict__ residue,
        const int* __restrict__ pres, const int* __restrict__ roles,
        const float* __restrict__ role_emb, const float* __restrict__ sw,
        unsigned short* __restrict__ Xh, float* __restrict__ rowmask,
        float* __restrict__ out_wm, float* __restrict__ out_mx,
        float* __restrict__ f_nsw) {
    int t  = blockIdx.x * 256 + threadIdx.x;
    int bl = t >> 7;
    int d4 = (t & 127) << 2;
    int b  = bl >> 10, l = bl & 1023;
    float nswv[KK];
    nsw_compute(sw, pres, b, nswv);
    float mk[KK], swr[KK];
    float ssum = 0.f, many = 0.f;
    #pragma unroll
    for (int k = 0; k < KK; ++k) {
        int bk = b*KK + k;
        bool valid = (residue[(size_t)bk*LL + l] != 0) && (pres[bk] != 0);
        mk[k]  = valid ? 1.f : 0.f;
        swr[k] = nswv[k] * mk[k];
        ssum += swr[k]; many += mk[k];
    }
    float inv = 1.f / fmaxf(ssum, EPSF);
    bool hasany = many > 0.5f;
    float wmx = 0.f, wmy = 0.f, wmz = 0.f, wmw = 0.f;
    float mxx = -1e9f, mxy = -1e9f, mxz = -1e9f, mxw = -1e9f;
    #pragma unroll
    for (int k = 0; k < KK; ++k) {
        int bk = b*KK + k;
        int role = roles[bk]; if (role < 0) role = 0;
        float4 sr = *(const float4*)(SR + ((size_t)bk*LL + l)*DD + d4);
        float4 re = *(const float4*)(role_emb + (size_t)role*DD + d4);
        float xx = (sr.x + re.x)*mk[k], xy = (sr.y + re.y)*mk[k];
        float xz = (sr.z + re.z)*mk[k], xw = (sr.w + re.w)*mk[k];
        ushort4 xs; xs.x = f2h(xx); xs.y = f2h(xy); xs.z = f2h(xz); xs.w = f2h(xw);
        *(ushort4*)(Xh + (size_t)(bl*KK + k)*DD + d4) = xs;
        float s = swr[k]*inv;
        wmx = fmaf(xx, s, wmx); wmy = fmaf(xy, s, wmy);
        wmz = fmaf(xz, s, wmz); wmw = fmaf(xw, s, wmw);
        if (mk[k] > 0.5f) {
            mxx = fmaxf(mxx, xx); mxy = fmaxf(mxy, xy);
            mxz = fmaxf(mxz, xz); mxw = fmaxf(mxw, xw);
        }
    }
    if (!hasany) { mxx = mxy = mxz = mxw = 0.f; }
    float4 wmv; wmv.x = wmx; wmv.y = wmy; wmv.z = wmz; wmv.w = wmw;
    float4 mxv; mxv.x = mxx; mxv.y = mxy; mxv.z = mxz; mxv.w = mxw;
    *(float4*)(out_wm + (size_t)bl*DD + d4) = wmv;
    *(float4*)(out_mx + (size_t)bl*DD + d4) = mxv;
    if (d4 == 0) {
        #pragma unroll
        for (int k = 0; k < KK; ++k) rowmask[bl*KK + k] = mk[k];
    }
    if (blockIdx.x == 0 && threadIdx.x < BB*KK) {
        int bb = threadIdx.x >> 2, kk2 = threadIdx.x & 3;
        float nv[KK];
        nsw_compute(sw, pres, bb, nv);
        f_nsw[threadIdx.x] = nv[kk2];
    }
}

// ---------------------------------------------------------------------------
// QKV GEMM: round-3 verified LDS kernel (~63 us), unchanged.
__global__ __launch_bounds__(512, 4) void gemm_qkv_8p(
        const unsigned short* __restrict__ A, const unsigned short* __restrict__ W,
        unsigned short* __restrict__ Cbase) {
    __shared__ __align__(16) unsigned short smem[36864];   // 3 bufs x 24 KiB
    const int tid  = threadIdx.x;
    const int wave = tid >> 6, lane = tid & 63;
    const int id = blockIdx.x;
    const int wg = (id & 7) * 192 + (id >> 3);
    const int m0 = (wg / 12) * 256;
    const int n0 = (wg % 12) * 128;
    const int wm = wave >> 1, wn = wave & 1;   // 4Mx2N wave grid
    const int fr = lane & 15, q = lane >> 4;
    const int srow = tid >> 2, scc = tid & 3;
    const int sswz = (scc ^ ((srow >> 1) & 3)) << 3;
    const unsigned short* Ag0 = A + (size_t)(m0 + srow)*512 + sswz;
    const unsigned short* Ag1 = Ag0 + (size_t)128*512;
    const unsigned short* Wg0 = W + (size_t)(n0 + srow)*512 + sswz;
    const int lA0 = tid << 3;
    const int lA1 = (tid + 512) << 3;
    int aoff[4], boff[4];
    #pragma unroll
    for (int mf = 0; mf < 4; ++mf) {
        int row = (wm << 6) + (mf << 4) + fr;
        aoff[mf] = (row << 5) + ((q ^ ((row >> 1) & 3)) << 3);
    }
    #pragma unroll
    for (int nf = 0; nf < 4; ++nf) {
        int row = (wn << 6) + (nf << 4) + fr;
        boff[nf] = (row << 5) + ((q ^ ((row >> 1) & 3)) << 3);
    }
    f32x4 acc[4][4] = {};

#define VMWAIT(N) asm volatile("s_waitcnt vmcnt(" #N ")" ::: "memory")
#define STAGE(tt) do { unsigned short* _d = smem + ((tt) % 3) * 12288; \
        const int _ko = (tt) << 5; \
        glds16(Ag0 + _ko, _d + lA0); glds16(Ag1 + _ko, _d + lA1); \
        glds16(Wg0 + _ko, _d + 8192 + lA0); } while (0)
#define MFROW(ai, areg) \
        acc[ai][0] = __builtin_amdgcn_mfma_f32_16x16x32_f16(areg, b0, acc[ai][0], 0, 0, 0); \
        acc[ai][1] = __builtin_amdgcn_mfma_f32_16x16x32_f16(areg, b1, acc[ai][1], 0, 0, 0); \
        acc[ai][2] = __builtin_amdgcn_mfma_f32_16x16x32_f16(areg, b2, acc[ai][2], 0, 0, 0); \
        acc[ai][3] = __builtin_amdgcn_mfma_f32_16x16x32_f16(areg, b3, acc[ai][3], 0, 0, 0);
#define TILE(t, STG, VM) do { \
        const unsigned short* _Ab = smem + ((t) % 3) * 12288; \
        const unsigned short* _Bb = _Ab + 8192; \
        VMWAIT(VM); \
        __builtin_amdgcn_s_barrier(); \
        __builtin_amdgcn_sched_barrier(0); \
        hfrag b0 = *(const hfrag*)(_Bb + boff[0]); \
        hfrag b1 = *(const hfrag*)(_Bb + boff[1]); \
        hfrag b2 = *(const hfrag*)(_Bb + boff[2]); \
        hfrag b3 = *(const hfrag*)(_Bb + boff[3]); \
        hfrag a0_ = *(const hfrag*)(_Ab + aoff[0]); \
        hfrag a1_ = *(const hfrag*)(_Ab + aoff[1]); \
        hfrag a2_ = *(const hfrag*)(_Ab + aoff[2]); \
        hfrag a3_ = *(const hfrag*)(_Ab + aoff[3]); \
        if (STG) STAGE((t) + 2); \
        __builtin_amdgcn_s_setprio(1); \
        MFROW(0, a0_) MFROW(1, a1_) MFROW(2, a2_) MFROW(3, a3_) \
        __builtin_amdgcn_s_setprio(0); \
    } while (0)

    STAGE(0); STAGE(1);
    #pragma unroll
    for (int t = 0; t < 14; ++t) TILE(t, 1, 3);
    TILE(14, 0, 3);
    TILE(15, 0, 0);
#undef TILE
#undef MFROW
#undef STAGE
#undef VMWAIT

    const int gc0 = n0 + (wn << 6);
    const int seg = gc0 >> 9;
    unsigned short* Cs = Cbase + (size_t)seg * ((size_t)MM * 512);
    const int cb = gc0 & 511;
    #pragma unroll
    for (int mf = 0; mf < 4; ++mf) {
        const int grow = m0 + (wm << 6) + (mf << 4) + (q << 2);
        #pragma unroll
        for (int nf = 0; nf < 4; ++nf) {
            const int col = cb + (nf << 4) + fr;
            #pragma unroll
            for (int r = 0; r < 4; ++r)
                Cs[(size_t)(grow + r) * 512 + col] = f2h(acc[mf][nf][r]);
        }
    }
}

// ---------------------------------------------------------------------------
// Tail GEMM template: C[M,512] = A[M,K] @ W[512,K]^T, 64x64 tiles, grid 1024
// (4 blocks/CU = 16 waves/CU: round-8's 128x128 versions ran 256 blocks =
// 1 wave/SIMD -> every rendezvous stall exposed; occupancy is the fix).
// 256 thr (2Mx2N waves, wave-tile 32x32), 3-buf LDS 24 KiB, XOR swizzle,
// single rendezvous/tile, uniform 2 loads/thread/stage -> counted vmcnt(2).
// EPI: 0 = fp32 store (ap) | 1 = bias+gelu fp16 (g1) | 2 = gate+fusion fp32.
template<int KT, int EPI>
__global__ __launch_bounds__(256, 4) void gemm_tail(
        const unsigned short* __restrict__ A, const unsigned short* __restrict__ W,
        void* __restrict__ Cv, const float* __restrict__ bias,
        const float* __restrict__ in_ap, const float* __restrict__ in_wm,
        const float* __restrict__ in_mx) {
    constexpr int K = KT * 32;
    __shared__ __align__(16) unsigned short smem[12288];   // 3 bufs x 8 KiB
    const int tid  = threadIdx.x;
    const int wave = tid >> 6, lane = tid & 63;
    // Bijective XCD swizzle (1024 blocks), n fastest (8 n-blocks of 64).
    const int id = blockIdx.x;
    const int wg = (id & 7) * 128 + (id >> 3);
    const int m0 = (wg >> 3) * 64;
    const int n0 = (wg & 7) * 64;
    const int wm = wave >> 1, wn = wave & 1;
    const int fr = lane & 15, q = lane >> 4;
    // Staging: A-tile 64x32 = 256 chunks (1/thread), B-tile same (1/thread).
    const int srow = tid >> 2, scc = tid & 3;
    const int sswz = (scc ^ ((srow >> 1) & 3)) << 3;
    const unsigned short* Ag = A + (size_t)(m0 + srow)*K + sswz;
    const unsigned short* Wg = W + (size_t)(n0 + srow)*K + sswz;
    const int lA = tid << 3;            // A region [0,2048) ushorts
    const int lB = 2048 + (tid << 3);   // B region [2048,4096)
    int aoff[2], boff[2];
    #pragma unroll
    for (int mf = 0; mf < 2; ++mf) {
        int row = (wm << 5) + (mf << 4) + fr;
        aoff[mf] = (row << 5) + ((q ^ ((row >> 1) & 3)) << 3);
    }
    #pragma unroll
    for (int nf = 0; nf < 2; ++nf) {
        int row = (wn << 5) + (nf << 4) + fr;
        boff[nf] = 2048 + (row << 5) + ((q ^ ((row >> 1) & 3)) << 3);
    }
    f32x4 acc[2][2] = {};

#define VMWAIT(N) asm volatile("s_waitcnt vmcnt(" #N ")" ::: "memory")
#define STAGE(tt) do { unsigned short* _d = smem + ((tt) % 3) * 4096; \
        const int _ko = (tt) << 5; \
        glds16(Ag + _ko, _d + lA); glds16(Wg + _ko, _d + lB); } while (0)
#define TILE(t, STG, VM) do { \
        const unsigned short* _Ab = smem + ((t) % 3) * 4096; \
        VMWAIT(VM); \
        __builtin_amdgcn_s_barrier(); \
        __builtin_amdgcn_sched_barrier(0); \
        hfrag b0 = *(const hfrag*)(_Ab + boff[0]); \
        hfrag b1 = *(const hfrag*)(_Ab + boff[1]); \
        hfrag a0_ = *(const hfrag*)(_Ab + aoff[0]); \
        hfrag a1_ = *(const hfrag*)(_Ab + aoff[1]); \
        if (STG) STAGE((t) + 2); \
        __builtin_amdgcn_s_setprio(1); \
        acc[0][0] = __builtin_amdgcn_mfma_f32_16x16x32_f16(a0_, b0, acc[0][0], 0, 0, 0); \
        acc[0][1] = __builtin_amdgcn_mfma_f32_16x16x32_f16(a0_, b1, acc[0][1], 0, 0, 0); \
        acc[1][0] = __builtin_amdgcn_mfma_f32_16x16x32_f16(a1_, b0, acc[1][0], 0, 0, 0); \
        acc[1][1] = __builtin_amdgcn_mfma_f32_16x16x32_f16(a1_, b1, acc[1][1], 0, 0, 0); \
        __builtin_amdgcn_s_setprio(0); \
    } while (0)

    STAGE(0); STAGE(1);
    #pragma unroll 3
    for (int t = 0; t < KT - 2; ++t) TILE(t, 1, 2);
    TILE(KT - 2, 0, 2);
    TILE(KT - 1, 0, 0);
#undef TILE
#undef STAGE
#undef VMWAIT

    #pragma unroll
    for (int mf = 0; mf < 2; ++mf) {
        const int grow = m0 + (wm << 5) + (mf << 4) + (q << 2);
        #pragma unroll
        for (int nf = 0; nf < 2; ++nf) {
            const int col = n0 + (wn << 5) + (nf << 4) + fr;
            #pragma unroll
            for (int r = 0; r < 4; ++r) {
                const int row = grow + r;
                float v = acc[mf][nf][r];
                if (EPI == 0) {
                    ((float*)Cv)[(size_t)row*512 + col] = v;
                } else if (EPI == 1) {
                    v += bias[col];
                    v = 0.5f * v * (1.f + erff(v * 0.70710678118654752f));
                    ((unsigned short*)Cv)[(size_t)row*512 + col] = f2h(v);
                } else {
                    float g = 1.f / (1.f + expf(-(v + bias[col])));
                    float ap = in_ap[(size_t)row*512 + col];
                    float wmv = in_wm[(size_t)row*512 + col];
                    float mxv = in_mx[(size_t)row*512 + col];
                    ((float*)Cv)[(size_t)row*512 + col] =
                        g*0.5f*(ap + wmv) + (1.f - g)*mxv + wmv;
                }
            }
        }
    }
}

// ---------------------------------------------------------------------------
// Per-(b,l) attention + pooled PV, 2 bl per block (grid 4096).  All 256
// threads active in QK^T (was 128); PV loads V as ushort4 (was ushort2);
// per-block sync cost amortized over 2 bl.
__global__ __launch_bounds__(256) void attn_kernel(
        const unsigned short* __restrict__ Qb, const unsigned short* __restrict__ Kb,
        const unsigned short* __restrict__ Vb,
        unsigned short* __restrict__ pooled,     // (BL,512) fp16
        const float* __restrict__ sw, const int* __restrict__ pres,
        const float* __restrict__ rowmask,
        float* __restrict__ attn_mean_out) {
    __shared__ float att[2][128];        // [blq][h*16 + q*4 + j]
    __shared__ float wv[2][32];          // [blq][h*4 + j]
    __shared__ float lw[2][KK], mk[2][KK], sp[2][KK];
    const int blp = blockIdx.x * 2;
    const int tid = threadIdx.x;
    if (tid < 8) {
        const int blq = tid >> 2, k = tid & 3;
        const int bl = blp + blq, b = bl >> 10;
        float nv[KK];
        nsw_compute(sw, pres, b, nv);
        lw[blq][k] = logf(fmaxf(nv[k], EPSF));
        float mkk[KK]; float ssum = 0.f;
        #pragma unroll
        for (int kk = 0; kk < KK; ++kk) {
            mkk[kk] = rowmask[bl*KK + kk];
            ssum += nv[kk]*mkk[kk];
        }
        mk[blq][k] = mkk[k];
        sp[blq][k] = nv[k]*mkk[k] / fmaxf(ssum, EPSF);   // swr' (mask-absorbed)
    }
    __syncthreads();
    {
        const int blq = tid >> 7, t2 = tid & 127;
        const int h = t2 >> 4, i = (t2 >> 2) & 3, j = t2 & 3;
        const int mb = (blp + blq) * KK;
        const unsigned short* qp = Qb + (size_t)(mb + i)*DD + h*HD;
        const unsigned short* kp = Kb + (size_t)(mb + j)*DD + h*HD;
        float s = 0.f;
        #pragma unroll
        for (int c = 0; c < 8; ++c) {
            hfrag qv = *(const hfrag*)(qp + c*8);
            hfrag kv = *(const hfrag*)(kp + c*8);
            #pragma unroll
            for (int e = 0; e < 8; ++e)
                s = fmaf((float)qv[e], (float)kv[e], s);
        }
        float lg = s * SCALE + lw[blq][j];
        att[blq][t2] = (mk[blq][j] > 0.5f) ? lg : -INFINITY;
    }
    __syncthreads();
    if (tid < 64) {
        const int blq = tid >> 5, t2 = tid & 31;
        float* ab = &att[blq][t2 * 4];
        float l0 = ab[0], l1 = ab[1], l2 = ab[2], l3 = ab[3];
        float m = fmaxf(fmaxf(l0, l1), fmaxf(l2, l3));
        if (m == -INFINITY) {
            ab[0] = ab[1] = ab[2] = ab[3] = 0.f;
        } else {
            float e0 = expf(l0 - m), e1 = expf(l1 - m), e2 = expf(l2 - m), e3 = expf(l3 - m);
            float inv = 1.f / (e0 + e1 + e2 + e3);
            ab[0] = e0*inv; ab[1] = e1*inv; ab[2] = e2*inv; ab[3] = e3*inv;
        }
    }
    __syncthreads();
    if (tid < 8) {
        const int blq = tid >> 2, k = tid & 3;
        float s = 0.f;
        for (int hi = 0; hi < 32; ++hi) s += att[blq][hi*4 + k];
        attn_mean_out[(size_t)(blp + blq)*KK + k] = s * (1.f/32.f);
    }
    if (tid < 64) {
        const int blq = tid >> 5, t2 = tid & 31;
        const int h = t2 >> 2, j = t2 & 3;
        wv[blq][t2] = sp[blq][0]*att[blq][h*16 + 0*4 + j]
                    + sp[blq][1]*att[blq][h*16 + 1*4 + j]
                    + sp[blq][2]*att[blq][h*16 + 2*4 + j]
                    + sp[blq][3]*att[blq][h*16 + 3*4 + j];
    }
    __syncthreads();
    {
        const int blq = tid >> 7, t2 = tid & 127;
        const int d4 = t2 << 2, h = d4 >> 6;
        const int mb = (blp + blq) * KK;
        float s0 = 0.f, s1 = 0.f, s2 = 0.f, s3 = 0.f;
        #pragma unroll
        for (int j = 0; j < KK; ++j) {
            float aj = wv[blq][h*4 + j];
            ushort4 vv = *(const ushort4*)(Vb + (size_t)(mb + j)*DD + d4);
            s0 = fmaf(aj, h2f(vv.x), s0);
            s1 = fmaf(aj, h2f(vv.y), s1);
            s2 = fmaf(aj, h2f(vv.z), s2);
            s3 = fmaf(aj, h2f(vv.w), s3);
        }
        ushort4 o; o.x = f2h(s0); o.y = f2h(s1); o.z = f2h(s2); o.w = f2h(s3);
        *(ushort4*)(pooled + (size_t)(blp + blq)*DD + d4) = o;
    }
}

// ---------------------------------------------------------------------------
// LN1 over [ap|wm|mx] (1536) per bl (unchanged).
__global__ __launch_bounds__(256) void ln1_kernel(
        const float* __restrict__ ap, const float* __restrict__ wm,
        const float* __restrict__ mx, const float* __restrict__ g,
        const float* __restrict__ bvec, unsigned short* __restrict__ hin) {
    const int bl = blockIdx.x * 4 + (threadIdx.x >> 6);
    const int lane = threadIdx.x & 63;
    const int c0 = lane * 8;
    float4 v[3][2];
    const float* srcs[3] = { ap + (size_t)bl*512 + c0,
                             wm + (size_t)bl*512 + c0,
                             mx + (size_t)bl*512 + c0 };
    float s = 0.f, s2 = 0.f;
    #pragma unroll
    for (int sg = 0; sg < 3; ++sg) {
        v[sg][0] = *(const float4*)(srcs[sg]);
        v[sg][1] = *(const float4*)(srcs[sg] + 4);
        #pragma unroll
        for (int e = 0; e < 8; ++e) {
            float x = ((const float*)v[sg])[e];
            s += x; s2 += x*x;
        }
    }
    #pragma unroll
    for (int o = 1; o < 64; o <<= 1) {
        s  += __shfl_xor(s,  o, 64);
        s2 += __shfl_xor(s2, o, 64);
    }
    const float mu = s * (1.f/(float)D3);
    const float var = s2 * (1.f/(float)D3) - mu*mu;
    const float rstd = rsqrtf(var + LN_EPSF);
    #pragma unroll
    for (int sg = 0; sg < 3; ++sg) {
        const int gofs = sg*512 + c0;
        #pragma unroll
        for (int h = 0; h < 2; ++h) {
            float4 g4 = *(const float4*)(g + gofs + h*4);
            float4 b4 = *(const float4*)(bvec + gofs + h*4);
            const float* sv = (const float*)&v[sg][h];
            ushort4 o4;
            o4.x = f2h((sv[0]-mu)*rstd*g4.x + b4.x);
            o4.y = f2h((sv[1]-mu)*rstd*g4.y + b4.y);
            o4.z = f2h((sv[2]-mu)*rstd*g4.z + b4.z);
            o4.w = f2h((sv[3]-mu)*rstd*g4.w + b4.w);
            *(ushort4*)(hin + (size_t)bl*D3 + gofs + h*4) = o4;
        }
    }
}

// ---------------------------------------------------------------------------
// Final LN over pre (512) per row (unchanged).
__global__ __launch_bounds__(256) void final_ln_kernel(
        const float* __restrict__ pre, const float* __restrict__ ng,
        const float* __restrict__ nb, float* __restrict__ fused) {
    const int row = blockIdx.x * 4 + (threadIdx.x >> 6);
    const int lane = threadIdx.x & 63;
    const int c0 = lane * 8;
    float4 p0 = *(const float4*)(pre + (size_t)row*512 + c0);
    float4 p1 = *(const float4*)(pre + (size_t)row*512 + c0 + 4);
    float s = 0.f, s2 = 0.f;
    const float* pv = (const float*)&p0;
    #pragma unroll
    for (int e = 0; e < 4; ++e) { s += pv[e]; s2 += pv[e]*pv[e]; }
    pv = (const float*)&p1;
    #pragma unroll
    for (int e = 0; e < 4; ++e) { s += pv[e]; s2 += pv[e]*pv[e]; }
    #pragma unroll
    for (int o = 1; o < 64; o <<= 1) {
        s  += __shfl_xor(s,  o, 64);
        s2 += __shfl_xor(s2, o, 64);
    }
    const float mu = s * (1.f/(float)DD);
    const float var = s2 * (1.f/(float)DD) - mu*mu;
    const float rstd = rsqrtf(var + LN_EPSF);
    float4 g0 = *(const float4*)(ng + c0), g1 = *(const float4*)(ng + c0 + 4);
    float4 b0 = *(const float4*)(nb + c0), b1 = *(const float4*)(nb + c0 + 4);
    float4 o0, o1;
    o0.x = (p0.x-mu)*rstd*g0.x + b0.x; o0.y = (p0.y-mu)*rstd*g0.y + b0.y;
    o0.z = (p0.z-mu)*rstd*g0.z + b0.z; o0.w = (p0.w-mu)*rstd*g0.w + b0.w;
    o1.x = (p1.x-mu)*rstd*g1.x + b1.x; o1.y = (p1.y-mu)*rstd*g1.y + b1.y;
    o1.z = (p1.z-mu)*rstd*g1.z + b1.z; o1.w = (p1.w-mu)*rstd*g1.w + b1.w;
    *(float4*)(fused + (size_t)row*512 + c0) = o0;
    *(float4*)(fused + (size_t)row*512 + c0 + 4) = o1;
}

// ---------------------------------------------------------------------------
extern "C" void kernel_launch(void* const* d_in, const int* in_sizes, int n_in,
                              void* d_out, int out_size, void* d_ws, size_t ws_size,
                              hipStream_t stream) {
    const float* SR      = (const float*)d_in[0];
    const int*   residue = (const int*)d_in[1];
    const float* sw      = (const float*)d_in[2];
    const int*   roles   = (const int*)d_in[3];
    const int*   pres    = (const int*)d_in[4];
    const float* role_emb= (const float*)d_in[5];
    const float* Wq      = (const float*)d_in[6];
    const float* Wk      = (const float*)d_in[7];
    const float* Wv      = (const float*)d_in[8];
    const float* Wo      = (const float*)d_in[9];
    const float* ln1_g   = (const float*)d_in[10];
    const float* ln1_b   = (const float*)d_in[11];
    const float* Wg1     = (const float*)d_in[12];
    const float* bg1     = (const float*)d_in[13];
    const float* Wg2     = (const float*)d_in[14];
    const float* bg2     = (const float*)d_in[15];
    const float* norm_g  = (const float*)d_in[16];
    const float* norm_b  = (const float*)d_in[17];

    float* out = (float*)d_out;
    const size_t BLD = (size_t)BL * DD;
    float* f_fused = out;
    float* f_ap    = out + BLD;
    float* f_wm    = out + 2*BLD;
    float* f_mx    = out + 3*BLD;
    float* f_am    = out + 4*BLD;
    float* f_nsw   = out + 4*BLD + (size_t)BL*KK;

    char* base = (char*)d_ws;
    const size_t MD2 = (size_t)MM * DD * 2;     // 32 MB per fp16 activation buffer
    unsigned short* Xh = (unsigned short*)(base);
    unsigned short* Qh = (unsigned short*)(base + MD2);       // Q|K|V contiguous:
    unsigned short* Kh = (unsigned short*)(base + 2*MD2);     //  QKV routing relies
    unsigned short* Vh = (unsigned short*)(base + 3*MD2);     //  on this layout
    unsigned short* Wb = (unsigned short*)(base + 4*MD2);     // 4 MB weights
    float* rmask = (float*)(base + 4*MD2 + (size_t)WTOT*2);
    unsigned short* PVh  = Xh;   // pooled V-combination (BL,512) fp16
                                 //  (X dead after QKV; g1 overwrites later)
    unsigned short* Hin  = Vh;   // (B,L,1536) fp16 (V dead after attn)
    unsigned short* Hbuf = Xh;   // gelu(h) (B,L,512) fp16 (pooled dead after ap_gemm)
    float* preb = (float*)Kh;    // pre-LN fusion (BL,512) fp32 (K dead after attn)
    const unsigned short* Wqkv = Wb;            // (1536, 512) = [Wq;Wk;Wv]
    const unsigned short* Woh  = Wb + 3*WSZ;
    const unsigned short* Wg1h = Wb + OG1;
    const unsigned short* Wg2h = Wb + OG2;

    dim3 blk(256);

    cvt_weights<<<WTOT/1024, blk, 0, stream>>>(Wq, Wk, Wv, Wo, Wg1, Wg2, Wb);
    buildx_kernel<<<(BL*128)/256, blk, 0, stream>>>(SR, residue, pres, roles, role_emb,
                                                    sw, Xh, rmask, f_wm, f_mx, f_nsw);

    // Fused QKV: round-3 verified 256x128 pipelined LDS kernel.
    gemm_qkv_8p<<<dim3(1536), dim3(512), 0, stream>>>(Xh, Wqkv, Qh);

    // Attention + pooled PV (pool-before-Wo), 2 bl/block: writes PVh.
    attn_kernel<<<dim3(BL/2), blk, 0, stream>>>(Qh, Kh, Vh, PVh, sw, pres, rmask, f_am);

    // f_ap = pooled @ Wo^T: 64x64 tiles, 1024 blocks (4/CU).
    gemm_tail<16, 0><<<dim3(1024), blk, 0, stream>>>(
        PVh, Woh, f_ap, nullptr, nullptr, nullptr, nullptr);

    // LN1 over [ap|wm|mx] -> hin fp16.
    ln1_kernel<<<dim3(BL/4), blk, 0, stream>>>(
        f_ap, f_wm, f_mx, ln1_g, ln1_b, Hin);

    // Wg1 + GELU: 64x64 tiles, 1024 blocks.
    gemm_tail<48, 1><<<dim3(1024), blk, 0, stream>>>(
        Hin, Wg1h, Hbuf, bg1, nullptr, nullptr, nullptr);

    // Wg2 + gate + fusion: 64x64 tiles, 1024 blocks.
    gemm_tail<16, 2><<<dim3(1024), blk, 0, stream>>>(
        Hbuf, Wg2h, preb, bg2, f_ap, f_wm, f_mx);

    // Final LN -> fused.
    final_ln_kernel<<<dim3(BL/4), blk, 0, stream>>>(
        preb, norm_g, norm_b, f_fused);
}